// Round 1
// baseline (73.415 us; speedup 1.0000x reference)
//
#include <hip/hip_runtime.h>
#include <hip/hip_bf16.h>

#define IN_DIM  512
#define OUT_DIM 512
#define BATCH   4096
#define NBASIS  9                     // NUM + K + 1 = 5 + 3 + 1
#define KDIM    (IN_DIM * NBASIS)     // 4608

// ws layout (bytes)
#define WOFF_WBF  0
#define WSZ_WBF   (OUT_DIM * KDIM * 2)            // 4,718,592
#define WOFF_ACTS (WOFF_WBF + WSZ_WBF)
#define WSZ_ACTS  (BATCH * KDIM * 2)              // 37,748,736
#define WOFF_PART (WOFF_ACTS + WSZ_ACTS)          // 42,467,328
// partials: 2 * 4096*512 * 4 = 16,777,216  -> total ~59.2 MB

typedef __attribute__((ext_vector_type(8))) short bf16x8;
typedef __attribute__((ext_vector_type(4))) float f32x4;

// ---------------- K1: weight fp32 -> bf16 ----------------
__global__ __launch_bounds__(256) void cast_w(const float4* __restrict__ w,
                                              short* __restrict__ wb) {
    int idx = blockIdx.x * 256 + threadIdx.x;      // 589824 float4s
    float4 v = w[idx];
    __hip_bfloat16 h[4] = {__float2bfloat16(v.x), __float2bfloat16(v.y),
                           __float2bfloat16(v.z), __float2bfloat16(v.w)};
    short4 s = *reinterpret_cast<short4*>(h);
    *reinterpret_cast<short4*>(wb + (size_t)idx * 4) = s;
}

// ---------------- K2: build acts (bf16) ----------------
// acts[b*4608 + j*512 + i] = x * (j<8 ? B3_j(x) : silu(x))
__global__ __launch_bounds__(256) void build_acts(const float* __restrict__ x,
                                                  const float* __restrict__ grid,
                                                  __hip_bfloat16* __restrict__ acts) {
    int idx = blockIdx.x * 256 + threadIdx.x;      // 0 .. 4096*512-1
    int b = idx >> 9;
    int i = idx & 511;
    float xv = x[idx];
    float g0 = grid[i * 6];
    float g5 = grid[i * 6 + 5];
    // uniform grid: h = (g5-g0)/5; s = (x-g0)/h in [0,5)
    float s = (xv - g0) * (5.0f / (g5 - g0));
    int mi = (int)s;                                // s >= 0 for in-domain x
    mi = mi < 0 ? 0 : (mi > 4 ? 4 : mi);
    float u = s - (float)mi;
    float u2 = u * u, u3 = u2 * u;
    const float c6 = 1.0f / 6.0f;
    float om = 1.0f - u;
    float b0 = om * om * om * c6;
    float b1 = (3.0f * u3 - 6.0f * u2 + 4.0f) * c6;
    float b2 = (-3.0f * u3 + 3.0f * u2 + 3.0f * u + 1.0f) * c6;
    float b3 = u3 * c6;
    float sil = xv / (1.0f + __expf(-xv));

    __hip_bfloat16* dst = acts + (size_t)b * KDIM + i;
#pragma unroll
    for (int j = 0; j < 8; ++j) {                   // select-chain: no runtime-indexed array
        int r = j - mi;
        float v = (r == 0) ? b0 : (r == 1) ? b1 : (r == 2) ? b2 : (r == 3) ? b3 : 0.0f;
        dst[j * IN_DIM] = __float2bfloat16(v * xv);
    }
    dst[8 * IN_DIM] = __float2bfloat16(sil * xv);
}

// ---------------- K3: bf16 MFMA GEMM, split-K=2 ----------------
// C_partial[sk][b][o] = sum_{k in split} acts[b][k] * W[o][k]
#define BM 128
#define BN 64
#define BK 64
#define SPLITK 2
#define KSPLIT (KDIM / SPLITK)   // 2304
#define KITERS (KSPLIT / BK)     // 36

__global__ __launch_bounds__(256) void gemm_kan(const short* __restrict__ A,
                                                const short* __restrict__ W,
                                                float* __restrict__ part) {
    __shared__ __align__(16) short As[BM * BK];    // 16 KB, linear [row][k]
    __shared__ __align__(16) short Ws[BN * BK];    // 8 KB,  linear [col][k]

    int bid = blockIdx.x;
    int sk = bid >> 8;            // 0..1
    int mn = bid & 255;
    int bm = mn >> 3;             // 0..31
    int bn = mn & 7;              // 0..7

    int tid  = threadIdx.x;
    int lane = tid & 63;
    int wid  = tid >> 6;          // 0..3
    int wr   = wid >> 1;          // wave row 0..1 (64 rows each)
    int wc   = wid & 1;           // wave col 0..1 (32 cols each)

    const short* Ab = A + (size_t)(bm * BM) * KDIM + sk * KSPLIT;
    const short* Wb = W + (size_t)(bn * BN) * KDIM + sk * KSPLIT;

    f32x4 acc[4][2];
#pragma unroll
    for (int m = 0; m < 4; ++m)
#pragma unroll
        for (int n = 0; n < 2; ++n) acc[m][n] = (f32x4){0.f, 0.f, 0.f, 0.f};

    int srow = lane >> 3;         // 0..7 (row within 8-row chunk)
    int scol = (lane & 7) * 8;    // k elem offset 0..56 (16B per lane)

    for (int kb = 0; kb < KITERS; ++kb) {
        int k0 = kb * BK;
        __syncthreads();          // prev iter's LDS readers done
        // stage A tile: 16 chunks of 1024B (wave-uniform LDS base + lane*16)
#pragma unroll
        for (int i = 0; i < 4; ++i) {
            int chunk = i * 4 + wid;              // 0..15
            int r = chunk * 8 + srow;             // 0..127
            __builtin_amdgcn_global_load_lds(
                (const __attribute__((address_space(1))) void*)(Ab + (size_t)r * KDIM + k0 + scol),
                (__attribute__((address_space(3))) void*)(&As[chunk * 512]),
                16, 0, 0);
        }
        // stage W tile: 8 chunks
#pragma unroll
        for (int i = 0; i < 2; ++i) {
            int chunk = i * 4 + wid;              // 0..7
            int r = chunk * 8 + srow;             // 0..63
            __builtin_amdgcn_global_load_lds(
                (const __attribute__((address_space(1))) void*)(Wb + (size_t)r * KDIM + k0 + scol),
                (__attribute__((address_space(3))) void*)(&Ws[chunk * 512]),
                16, 0, 0);
        }
        __syncthreads();          // vmcnt(0) drain + barrier: LDS ready

#pragma unroll
        for (int ks = 0; ks < 2; ++ks) {
            int kk = ks * 32 + (lane >> 4) * 8;   // k offset for this lane
            bf16x8 af[4], wf[2];
#pragma unroll
            for (int m = 0; m < 4; ++m) {
                int row = wr * 64 + m * 16 + (lane & 15);
                af[m] = *reinterpret_cast<const bf16x8*>(&As[row * BK + kk]);
            }
#pragma unroll
            for (int n = 0; n < 2; ++n) {
                int col = wc * 32 + n * 16 + (lane & 15);
                wf[n] = *reinterpret_cast<const bf16x8*>(&Ws[col * BK + kk]);
            }
#pragma unroll
            for (int m = 0; m < 4; ++m)
#pragma unroll
                for (int n = 0; n < 2; ++n)
                    acc[m][n] = __builtin_amdgcn_mfma_f32_16x16x32_bf16(af[m], wf[n], acc[m][n], 0, 0, 0);
        }
    }

    // epilogue: C/D layout col = lane&15, row = (lane>>4)*4 + reg
    float* p = part + (size_t)sk * BATCH * OUT_DIM;
    int crow0 = bm * BM + wr * 64 + (lane >> 4) * 4;
    int ccol0 = bn * BN + wc * 32 + (lane & 15);
#pragma unroll
    for (int m = 0; m < 4; ++m)
#pragma unroll
        for (int n = 0; n < 2; ++n)
#pragma unroll
            for (int r = 0; r < 4; ++r)
                p[(size_t)(crow0 + m * 16 + r) * OUT_DIM + ccol0 + n * 16] = acc[m][n][r];
}

// ---------------- K4: reduce partials + bias ----------------
__global__ __launch_bounds__(256) void reduce_out(const float4* __restrict__ p0,
                                                  const float4* __restrict__ p1,
                                                  const float4* __restrict__ bias,
                                                  float4* __restrict__ out) {
    int idx = blockIdx.x * 256 + threadIdx.x;     // 524288 float4s
    float4 a = p0[idx];
    float4 b = p1[idx];
    float4 c = bias[idx & 127];                   // OUT_DIM/4 = 128
    float4 o;
    o.x = a.x + b.x + c.x;
    o.y = a.y + b.y + c.y;
    o.z = a.z + b.z + c.z;
    o.w = a.w + b.w + c.w;
    out[idx] = o;
}

extern "C" void kernel_launch(void* const* d_in, const int* in_sizes, int n_in,
                              void* d_out, int out_size, void* d_ws, size_t ws_size,
                              hipStream_t stream) {
    (void)in_sizes; (void)n_in; (void)out_size; (void)ws_size;
    const float* x      = (const float*)d_in[0];
    const float* grid   = (const float*)d_in[1];
    const float* weight = (const float*)d_in[2];
    const float* bias   = (const float*)d_in[3];

    char* ws = (char*)d_ws;
    short*          wbf  = (short*)(ws + WOFF_WBF);
    __hip_bfloat16* acts = (__hip_bfloat16*)(ws + WOFF_ACTS);
    float*          part = (float*)(ws + WOFF_PART);

    cast_w<<<(OUT_DIM * KDIM / 4) / 256, 256, 0, stream>>>((const float4*)weight, wbf);
    build_acts<<<(BATCH * IN_DIM) / 256, 256, 0, stream>>>(x, grid, acts);
    gemm_kan<<<(BATCH / BM) * (OUT_DIM / BN) * SPLITK, 256, 0, stream>>>(
        (const short*)acts, wbf, part);
    reduce_out<<<(BATCH * OUT_DIM / 4) / 256, 256, 0, stream>>>(
        (const float4*)part, (const float4*)(part + BATCH * OUT_DIM),
        (const float4*)bias, (float4*)d_out);
}

// Round 3
// 54.574 us; speedup vs baseline: 1.3452x; 1.3452x over previous
//
#include <hip/hip_runtime.h>
#include <hip/hip_bf16.h>

#define IN_DIM  512
#define OUT_DIM 512
#define BATCH   4096
#define NBASIS  9                     // NUM + K + 1 = 5 + 3 + 1
#define KDIM    (IN_DIM * NBASIS)     // 4608

// ws layout (bytes)
#define WOFF_WBF  0
#define WSZ_WBF   (OUT_DIM * KDIM * 2)            // 4,718,592
#define WOFF_ACTS (WOFF_WBF + WSZ_WBF)
#define WSZ_ACTS  (BATCH * KDIM * 2)              // 37,748,736
#define WOFF_PART (WOFF_ACTS + WSZ_ACTS)          // 42,467,328
// partials: SPLITK * 4096*512*4 bytes (splitK=4 -> 33.5 MB, total ~76 MB;
// runtime falls back to splitK=2 if ws_size too small)

typedef __attribute__((ext_vector_type(8))) short bf16x8;
typedef __attribute__((ext_vector_type(4))) float f32x4;

#define NW_BLOCKS 2304   // weight-cast blocks: 589824 float4 / 256

// ---------------- K1: fused weight cast + acts build ----------------
__global__ __launch_bounds__(256) void prep(const float4* __restrict__ w,
                                            short* __restrict__ wb,
                                            const float* __restrict__ x,
                                            const float* __restrict__ grid,
                                            __hip_bfloat16* __restrict__ acts) {
    int blk = blockIdx.x;
    if (blk < NW_BLOCKS) {
        int idx = blk * 256 + threadIdx.x;             // 589824 float4s
        float4 v = w[idx];
        __hip_bfloat16 h[4] = {__float2bfloat16(v.x), __float2bfloat16(v.y),
                               __float2bfloat16(v.z), __float2bfloat16(v.w)};
        *reinterpret_cast<short4*>(wb + (size_t)idx * 4) = *reinterpret_cast<short4*>(h);
        return;
    }
    int idx = (blk - NW_BLOCKS) * 256 + threadIdx.x;   // 0 .. 4096*512-1
    int b = idx >> 9;
    int i = idx & 511;
    float xv = x[idx];
    float g0 = grid[i * 6];
    float g5 = grid[i * 6 + 5];
    float s = (xv - g0) * (5.0f / (g5 - g0));
    int mi = (int)s;
    mi = mi < 0 ? 0 : (mi > 4 ? 4 : mi);
    float u = s - (float)mi;
    float u2 = u * u, u3 = u2 * u;
    const float c6 = 1.0f / 6.0f;
    float om = 1.0f - u;
    float b0 = om * om * om * c6;
    float b1 = (3.0f * u3 - 6.0f * u2 + 4.0f) * c6;
    float b2 = (-3.0f * u3 + 3.0f * u2 + 3.0f * u + 1.0f) * c6;
    float b3 = u3 * c6;
    float sil = xv / (1.0f + __expf(-xv));

    __hip_bfloat16* dst = acts + (size_t)b * KDIM + i;
#pragma unroll
    for (int j = 0; j < 8; ++j) {
        int r = j - mi;
        float v = (r == 0) ? b0 : (r == 1) ? b1 : (r == 2) ? b2 : (r == 3) ? b3 : 0.0f;
        dst[j * IN_DIM] = __float2bfloat16(v * xv);
    }
    dst[8 * IN_DIM] = __float2bfloat16(sil * xv);
}

// ---------------- K2: bf16 MFMA GEMM, 128x128 tile, split-K ----------------
// grid = 128 * SPLITK blocks; bid = sk*128 + bm*4 + bn
#define BM 128
#define BN 128
#define BK 64

__global__ __launch_bounds__(256) void gemm_kan(const short* __restrict__ A,
                                                const short* __restrict__ W,
                                                float* __restrict__ part,
                                                int ksplit) {
    __shared__ __align__(16) short As[BM * BK];    // 16 KB, [row][64], XOR-swizzled slots
    __shared__ __align__(16) short Ws[BN * BK];    // 16 KB

    int bid = blockIdx.x;
    int sk = bid >> 7;
    int mn = bid & 127;
    int bm = mn >> 2;             // 0..31
    int bn = mn & 3;              // 0..3

    int tid  = threadIdx.x;
    int lane = tid & 63;
    int wid  = tid >> 6;          // 0..3
    int wr   = wid >> 1;          // wave row 0..1 (64 rows)
    int wc   = wid & 1;           // wave col 0..1 (64 cols)

    const short* Ab = A + (size_t)(bm * BM) * KDIM + (size_t)sk * ksplit;
    const short* Wb = W + (size_t)(bn * BN) * KDIM + (size_t)sk * ksplit;
    int kiters = ksplit >> 6;

    f32x4 acc[4][4];
#pragma unroll
    for (int m = 0; m < 4; ++m)
#pragma unroll
        for (int n = 0; n < 4; ++n) acc[m][n] = (f32x4){0.f, 0.f, 0.f, 0.f};

    // staging: per issue, wave w covers rows i*32 + w*8 + (lane>>3), slot lane&7.
    // LDS slot s of row r holds global col8 (s ^ (r&7)); r&7 == lane>>3 here,
    // so source col8 = (lane&7) ^ (lane>>3).  (rule #21: linear LDS dest,
    // inverse-swizzled global source, swizzled read)
    int srow = lane >> 3;                       // 0..7
    int scol = ((lane & 7) ^ srow) * 8;         // swizzled source k-offset (elems)

    for (int kb = 0; kb < kiters; ++kb) {
        int k0 = kb * BK;
        __syncthreads();          // prev iter's LDS readers done
#pragma unroll
        for (int i = 0; i < 4; ++i) {           // A tile: 128 rows
            int r0 = i * 32 + wid * 8;
            __builtin_amdgcn_global_load_lds(
                (const __attribute__((address_space(1))) void*)(Ab + (size_t)(r0 + srow) * KDIM + k0 + scol),
                (__attribute__((address_space(3))) void*)(&As[r0 * 64]),
                16, 0, 0);
        }
#pragma unroll
        for (int i = 0; i < 4; ++i) {           // W tile: 128 rows
            int r0 = i * 32 + wid * 8;
            __builtin_amdgcn_global_load_lds(
                (const __attribute__((address_space(1))) void*)(Wb + (size_t)(r0 + srow) * KDIM + k0 + scol),
                (__attribute__((address_space(3))) void*)(&Ws[r0 * 64]),
                16, 0, 0);
        }
        __syncthreads();          // vmcnt(0) drain + barrier: LDS ready

        int g = lane >> 4;        // 0..3
        int fr = lane & 15;
#pragma unroll
        for (int ks = 0; ks < 2; ++ks) {
            int kk8 = ks * 4 + g;               // 16B slot index along K
            bf16x8 af[4], wf[4];
#pragma unroll
            for (int m = 0; m < 4; ++m) {
                int row = wr * 64 + m * 16 + fr;
                int slot = kk8 ^ (row & 7);
                af[m] = *reinterpret_cast<const bf16x8*>(&As[row * 64 + slot * 8]);
            }
#pragma unroll
            for (int n = 0; n < 4; ++n) {
                int col = wc * 64 + n * 16 + fr;
                int slot = kk8 ^ (col & 7);
                wf[n] = *reinterpret_cast<const bf16x8*>(&Ws[col * 64 + slot * 8]);
            }
#pragma unroll
            for (int m = 0; m < 4; ++m)
#pragma unroll
                for (int n = 0; n < 4; ++n)
                    acc[m][n] = __builtin_amdgcn_mfma_f32_16x16x32_bf16(af[m], wf[n], acc[m][n], 0, 0, 0);
        }
    }

    // epilogue: C/D layout col = lane&15, row = (lane>>4)*4 + reg
    float* p = part + (size_t)sk * BATCH * OUT_DIM;
    int crow0 = bm * BM + wr * 64 + (lane >> 4) * 4;
    int ccol0 = bn * BN + wc * 64 + (lane & 15);
#pragma unroll
    for (int m = 0; m < 4; ++m)
#pragma unroll
        for (int n = 0; n < 4; ++n)
#pragma unroll
            for (int r = 0; r < 4; ++r)
                p[(size_t)(crow0 + m * 16 + r) * OUT_DIM + ccol0 + n * 16] = acc[m][n][r];
}

// ---------------- K3: reduce partials + bias ----------------
__global__ __launch_bounds__(256) void reduce_out(const float4* __restrict__ part,
                                                  const float4* __restrict__ bias,
                                                  float4* __restrict__ out,
                                                  int nsplit) {
    int idx = blockIdx.x * 256 + threadIdx.x;     // 524288 float4s
    const int stride = BATCH * OUT_DIM / 4;
    float4 o = bias[idx & 127];                   // OUT_DIM/4 = 128
#pragma unroll 4
    for (int s = 0; s < nsplit; ++s) {
        float4 a = part[(size_t)s * stride + idx];
        o.x += a.x; o.y += a.y; o.z += a.z; o.w += a.w;
    }
    out[idx] = o;
}

extern "C" void kernel_launch(void* const* d_in, const int* in_sizes, int n_in,
                              void* d_out, int out_size, void* d_ws, size_t ws_size,
                              hipStream_t stream) {
    (void)in_sizes; (void)n_in; (void)out_size;
    const float* x      = (const float*)d_in[0];
    const float* grid   = (const float*)d_in[1];
    const float* weight = (const float*)d_in[2];
    const float* bias   = (const float*)d_in[3];

    char* ws = (char*)d_ws;
    short*          wbf  = (short*)(ws + WOFF_WBF);
    __hip_bfloat16* acts = (__hip_bfloat16*)(ws + WOFF_ACTS);
    float*          part = (float*)(ws + WOFF_PART);

    // split-K=4 if workspace permits, else 2 (round-1-proven footprint)
    size_t need4 = (size_t)WOFF_PART + 4ull * BATCH * OUT_DIM * 4;
    int splitk = (ws_size >= need4) ? 4 : 2;
    int ksplit = KDIM / splitk;

    prep<<<NW_BLOCKS + (BATCH * IN_DIM) / 256, 256, 0, stream>>>(
        (const float4*)weight, wbf, x, grid, acts);
    gemm_kan<<<128 * splitk, 256, 0, stream>>>((const short*)acts, wbf, part, ksplit);
    reduce_out<<<(BATCH * OUT_DIM / 4) / 256, 256, 0, stream>>>(
        (const float4*)part, (const float4*)bias, (float4*)d_out, splitk);
}

// Round 4
// 47.851 us; speedup vs baseline: 1.5342x; 1.1405x over previous
//
#include <hip/hip_runtime.h>
#include <hip/hip_bf16.h>

#define IN_DIM  512
#define OUT_DIM 512
#define BATCH   4096
#define NBASIS  9                     // NUM + K + 1 = 5 + 3 + 1
#define KDIM    (IN_DIM * NBASIS)     // 4608

// ws layout (bytes)
#define WOFF_WBF  0
#define WSZ_WBF   (OUT_DIM * KDIM * 2)            // 4,718,592
#define WOFF_ACTS (WOFF_WBF + WSZ_WBF)
#define WSZ_ACTS  (BATCH * KDIM * 2)              // 37,748,736
#define WOFF_PART (WOFF_ACTS + WSZ_ACTS)          // 42,467,328
// partials (fp16): SPLITK * 4096*512*2 bytes (splitK=4 -> 16.8 MB)

typedef __attribute__((ext_vector_type(8))) short bf16x8;
typedef __attribute__((ext_vector_type(4))) float f32x4;
typedef __attribute__((ext_vector_type(8))) _Float16 h16x8;

#define NW_BLOCKS 2304   // weight-cast blocks: 589824 float4 / 256

// ---------------- K1: fused weight cast + acts build ----------------
__global__ __launch_bounds__(256) void prep(const float4* __restrict__ w,
                                            short* __restrict__ wb,
                                            const float* __restrict__ x,
                                            const float* __restrict__ grid,
                                            __hip_bfloat16* __restrict__ acts) {
    int blk = blockIdx.x;
    if (blk < NW_BLOCKS) {
        int idx = blk * 256 + threadIdx.x;             // 589824 float4s
        float4 v = w[idx];
        __hip_bfloat16 h[4] = {__float2bfloat16(v.x), __float2bfloat16(v.y),
                               __float2bfloat16(v.z), __float2bfloat16(v.w)};
        *reinterpret_cast<short4*>(wb + (size_t)idx * 4) = *reinterpret_cast<short4*>(h);
        return;
    }
    int idx = (blk - NW_BLOCKS) * 256 + threadIdx.x;   // 0 .. 4096*512-1
    int b = idx >> 9;
    int i = idx & 511;
    float xv = x[idx];
    float g0 = grid[i * 6];
    float g5 = grid[i * 6 + 5];
    float s = (xv - g0) * (5.0f / (g5 - g0));
    int mi = (int)s;
    mi = mi < 0 ? 0 : (mi > 4 ? 4 : mi);
    float u = s - (float)mi;
    float u2 = u * u, u3 = u2 * u;
    const float c6 = 1.0f / 6.0f;
    float om = 1.0f - u;
    float b0 = om * om * om * c6;
    float b1 = (3.0f * u3 - 6.0f * u2 + 4.0f) * c6;
    float b2 = (-3.0f * u3 + 3.0f * u2 + 3.0f * u + 1.0f) * c6;
    float b3 = u3 * c6;
    float sil = xv / (1.0f + __expf(-xv));

    __hip_bfloat16* dst = acts + (size_t)b * KDIM + i;
#pragma unroll
    for (int j = 0; j < 8; ++j) {
        int r = j - mi;
        float v = (r == 0) ? b0 : (r == 1) ? b1 : (r == 2) ? b2 : (r == 3) ? b3 : 0.0f;
        dst[j * IN_DIM] = __float2bfloat16(v * xv);
    }
    dst[8 * IN_DIM] = __float2bfloat16(sil * xv);
}

// ---------------- K2: bf16 MFMA GEMM, 128x128 tile, split-K ----------------
// logical tile l = sk*128 + bm*4 + bn; XCD-swizzled so each XCD owns 64
// consecutive l (16 bm x 4 bn, one sk) -> A-panel fetched once per XCD.
#define BM 128
#define BN 128
#define BK 64

__global__ __launch_bounds__(256) void gemm_kan(const short* __restrict__ A,
                                                const short* __restrict__ W,
                                                _Float16* __restrict__ part,
                                                int ksplit) {
    __shared__ __align__(16) short As[BM * BK];    // 16 KB, [row][64], XOR-swizzled slots
    __shared__ __align__(16) short Ws[BN * BK];    // 16 KB

    // XCD-aware swizzle (bijective: gridDim.x % 8 == 0 for splitk in {2,4})
    int nper = gridDim.x >> 3;
    int bid  = (blockIdx.x & 7) * nper + (blockIdx.x >> 3);

    int sk = bid >> 7;
    int mn = bid & 127;
    int bm = mn >> 2;             // 0..31
    int bn = mn & 3;              // 0..3

    int tid  = threadIdx.x;
    int lane = tid & 63;
    int wid  = tid >> 6;          // 0..3
    int wr   = wid >> 1;          // wave row 0..1 (64 rows)
    int wc   = wid & 1;           // wave col 0..1 (64 cols)

    const short* Ab = A + (size_t)(bm * BM) * KDIM + (size_t)sk * ksplit;
    const short* Wb = W + (size_t)(bn * BN) * KDIM + (size_t)sk * ksplit;
    int kiters = ksplit >> 6;

    f32x4 acc[4][4];
#pragma unroll
    for (int m = 0; m < 4; ++m)
#pragma unroll
        for (int n = 0; n < 4; ++n) acc[m][n] = (f32x4){0.f, 0.f, 0.f, 0.f};

    // staging: per issue, wave w covers rows i*32 + w*8 + (lane>>3), slot lane&7.
    // LDS slot s of row r holds global col8 (s ^ (r&7)); r&7 == lane>>3 here,
    // so source col8 = (lane&7) ^ (lane>>3).  (rule #21: linear LDS dest,
    // inverse-swizzled global source, swizzled read)
    int srow = lane >> 3;                       // 0..7
    int scol = ((lane & 7) ^ srow) * 8;         // swizzled source k-offset (elems)

    for (int kb = 0; kb < kiters; ++kb) {
        int k0 = kb * BK;
        __syncthreads();          // prev iter's LDS readers done
#pragma unroll
        for (int i = 0; i < 4; ++i) {           // A tile: 128 rows
            int r0 = i * 32 + wid * 8;
            __builtin_amdgcn_global_load_lds(
                (const __attribute__((address_space(1))) void*)(Ab + (size_t)(r0 + srow) * KDIM + k0 + scol),
                (__attribute__((address_space(3))) void*)(&As[r0 * 64]),
                16, 0, 0);
        }
#pragma unroll
        for (int i = 0; i < 4; ++i) {           // W tile: 128 rows
            int r0 = i * 32 + wid * 8;
            __builtin_amdgcn_global_load_lds(
                (const __attribute__((address_space(1))) void*)(Wb + (size_t)(r0 + srow) * KDIM + k0 + scol),
                (__attribute__((address_space(3))) void*)(&Ws[r0 * 64]),
                16, 0, 0);
        }
        __syncthreads();          // vmcnt(0) drain + barrier: LDS ready

        int g = lane >> 4;        // 0..3
        int fr = lane & 15;
#pragma unroll
        for (int ks = 0; ks < 2; ++ks) {
            int kk8 = ks * 4 + g;               // 16B slot index along K
            bf16x8 af[4], wf[4];
#pragma unroll
            for (int m = 0; m < 4; ++m) {
                int row = wr * 64 + m * 16 + fr;
                int slot = kk8 ^ (row & 7);
                af[m] = *reinterpret_cast<const bf16x8*>(&As[row * 64 + slot * 8]);
            }
#pragma unroll
            for (int n = 0; n < 4; ++n) {
                int col = wc * 64 + n * 16 + fr;
                int slot = kk8 ^ (col & 7);
                wf[n] = *reinterpret_cast<const bf16x8*>(&Ws[col * 64 + slot * 8]);
            }
#pragma unroll
            for (int m = 0; m < 4; ++m)
#pragma unroll
                for (int n = 0; n < 4; ++n)
                    acc[m][n] = __builtin_amdgcn_mfma_f32_16x16x32_bf16(af[m], wf[n], acc[m][n], 0, 0, 0);
        }
    }

    // epilogue: C/D layout col = lane&15, row = (lane>>4)*4 + reg; fp16 partials
    _Float16* p = part + (size_t)sk * BATCH * OUT_DIM;
    int crow0 = bm * BM + wr * 64 + (lane >> 4) * 4;
    int ccol0 = bn * BN + wc * 64 + (lane & 15);
#pragma unroll
    for (int m = 0; m < 4; ++m)
#pragma unroll
        for (int n = 0; n < 4; ++n)
#pragma unroll
            for (int r = 0; r < 4; ++r)
                p[(size_t)(crow0 + m * 16 + r) * OUT_DIM + ccol0 + n * 16] =
                    (_Float16)acc[m][n][r];
}

// ---------------- K3: reduce fp16 partials + bias ----------------
__global__ __launch_bounds__(256) void reduce_out(const _Float16* __restrict__ part,
                                                  const float4* __restrict__ bias,
                                                  float4* __restrict__ out,
                                                  int nsplit) {
    int idx = blockIdx.x * 256 + threadIdx.x;     // 0..262143, 8 outputs each
    const size_t stride = (size_t)BATCH * OUT_DIM;
    float4 b0 = bias[(idx & 63) * 2];             // col = (idx%64)*8
    float4 b1 = bias[(idx & 63) * 2 + 1];
    float a[8] = {b0.x, b0.y, b0.z, b0.w, b1.x, b1.y, b1.z, b1.w};
#pragma unroll 4
    for (int s = 0; s < nsplit; ++s) {
        h16x8 v = *reinterpret_cast<const h16x8*>(part + (size_t)s * stride + (size_t)idx * 8);
#pragma unroll
        for (int j = 0; j < 8; ++j) a[j] += (float)v[j];
    }
    out[idx * 2]     = (float4){a[0], a[1], a[2], a[3]};
    out[idx * 2 + 1] = (float4){a[4], a[5], a[6], a[7]};
}

extern "C" void kernel_launch(void* const* d_in, const int* in_sizes, int n_in,
                              void* d_out, int out_size, void* d_ws, size_t ws_size,
                              hipStream_t stream) {
    (void)in_sizes; (void)n_in; (void)out_size;
    const float* x      = (const float*)d_in[0];
    const float* grid   = (const float*)d_in[1];
    const float* weight = (const float*)d_in[2];
    const float* bias   = (const float*)d_in[3];

    char* ws = (char*)d_ws;
    short*          wbf  = (short*)(ws + WOFF_WBF);
    __hip_bfloat16* acts = (__hip_bfloat16*)(ws + WOFF_ACTS);
    _Float16*       part = (_Float16*)(ws + WOFF_PART);

    size_t need4 = (size_t)WOFF_PART + 4ull * BATCH * OUT_DIM * 2;
    int splitk = (ws_size >= need4) ? 4 : 2;
    int ksplit = KDIM / splitk;

    prep<<<NW_BLOCKS + (BATCH * IN_DIM) / 256, 256, 0, stream>>>(
        (const float4*)weight, wbf, x, grid, acts);
    gemm_kan<<<128 * splitk, 256, 0, stream>>>((const short*)acts, wbf, part, ksplit);
    reduce_out<<<(BATCH * OUT_DIM / 8) / 256, 256, 0, stream>>>(
        part, (const float4*)bias, (float4*)d_out, splitk);
}